// Round 4
// baseline (73.965 us; speedup 1.0000x reference)
//
#include <hip/hip_runtime.h>
#include <hip/hip_bf16.h>
#include <math.h>

typedef __attribute__((ext_vector_type(8))) short short8;
typedef __attribute__((ext_vector_type(16))) float f32x16;

union U {
    unsigned u[4];
    short8 s;
};

struct FragH {         // one component (re or im) bf16 operand, 2 k-tiles
    U f[2];
};

static __device__ __forceinline__ unsigned short f2bf(float x) {
    __bf16 b = (__bf16)x;                       // RNE, native v_cvt on gfx950
    return __builtin_bit_cast(unsigned short, b);
}
static __device__ __forceinline__ float bf2f(unsigned short h) {
    return __builtin_bit_cast(float, (unsigned)h << 16);
}
static __device__ __forceinline__ unsigned packbf(float a, float b) {
    return (unsigned)f2bf(a) | ((unsigned)f2bf(b) << 16);
}

#define MFMA(A, B, C) __builtin_amdgcn_mfma_f32_32x32x16_bf16((A).s, (B).s, (C), 0, 0, 0)

// ---------------------------------------------------------------------------
// Workspace layout (bytes):
//   0      : tabs  float2[4096]  (F, Finv, tw, twinv -- legacy layout for kf_kernel)
//   32768  : T1    float2[1024]  (tw permuted to C/D fragment order)
//   49152  : Ftab  uint4 [384]   (bf16 fragment tables: re, im, +sin; hi only)
//   65536  : kf_cd float2[128*1024] (filter spectrum, permuted to C/D order)
// ---------------------------------------------------------------------------

__global__ __launch_bounds__(256) void fft_tables(float2* tabs, float2* T1, uint4* Ftab) {
    int gid = blockIdx.x * 256 + threadIdx.x;       // grid 16*256 = 4096
    if (gid < 1024) {
        int i = gid;
        int r = i >> 5, c = i & 31;
        float s32, c32;
        sincospif((float)((r * c) & 31) / 16.0f, &s32, &c32);
        s32 = -s32;                                  // exp(-2pi i rc/32)
        tabs[i]        = make_float2(c32,  s32);     // F
        tabs[1024 + i] = make_float2(c32, -s32);     // Finv
        float sN, cN;
        sincospif((float)(r * c) / 512.0f, &sN, &cN);
        sN = -sN;                                    // exp(-2pi i rc/1024)
        tabs[2048 + i] = make_float2(cN / 1024.0f, sN / 1024.0f);  // tw
        tabs[3072 + i] = make_float2(cN, -sN);                     // twinv
        // T1[m][l] = tw[l&31][row(m,l)] (tw symmetric)
        int m = i >> 6, l = i & 63;
        int row = (m & 3) + 8 * (m >> 2) + 4 * (l >> 5);
        int prod = (l & 31) * row;
        float st, ct;
        sincospif((float)prod / 512.0f, &st, &ct);
        T1[i] = make_float2(ct / 1024.0f, -st / 1024.0f);
    }
    if (gid < 1536) {
        // Ftab: 3 comps x 2 ktiles x 64 lanes x 4 vgprs, packed bf16 pairs.
        // comp 0: re(F)=cos ; 1: im(F)=-sin ; 2: +sin
        int c = gid >> 9;
        int rem = gid & 511;
        int t = rem >> 8;
        int sub = rem & 255;
        int l = sub >> 2;
        int v = sub & 3;
        int k0 = 16 * t + 8 * (l >> 5) + 2 * v;
        int j = l & 31;
        unsigned short sh[2];
        for (int q = 0; q < 2; q++) {
            int k = k0 + q;
            float sa, ca;
            sincospif((float)((k * j) & 31) / 16.0f, &sa, &ca);
            float base = (c == 0) ? ca : ((c == 1) ? -sa : sa);
            sh[q] = f2bf(base);
        }
        ((unsigned*)Ftab)[((c * 2 + t) * 64 + l) * 4 + v] =
            (unsigned)sh[0] | ((unsigned)sh[1] << 16);
    }
}

// Filter spectrum kfT[h][k1][k2] = FFT_1024(k[h])[32*k2+k1], written permuted:
// kf_cd[h][m][l] = kfT[h][l&31][row(m,l)]
__global__ __launch_bounds__(256) void kf_kernel(const float* __restrict__ kin,
                                                 const float2* __restrict__ tabs,
                                                 float2* __restrict__ kf_cd) {
    __shared__ float  sx[1024];
    __shared__ float2 sA[1024];
    const int h = blockIdx.x, t = threadIdx.x;
    for (int i = t; i < 1024; i += 256) sx[i] = kin[h * 1024 + i];
    __syncthreads();
    const int r = t >> 3, c0 = (t & 7) << 2;

    float2 acc[4];
    for (int j = 0; j < 4; j++) acc[j] = make_float2(0.f, 0.f);
    #pragma unroll 8
    for (int n1 = 0; n1 < 32; n1++) {
        float2 f = tabs[r * 32 + n1];
        for (int j = 0; j < 4; j++) {
            float xv = sx[n1 * 32 + c0 + j];
            acc[j].x += f.x * xv;
            acc[j].y += f.y * xv;
        }
    }
    for (int j = 0; j < 4; j++) {
        float2 w = tabs[3072 + r * 32 + c0 + j];   // conj -> exp(-2pi i rc/N)
        sA[r * 32 + c0 + j] = make_float2(acc[j].x * w.x + acc[j].y * w.y,
                                          acc[j].y * w.x - acc[j].x * w.y);
    }
    __syncthreads();
    for (int j = 0; j < 4; j++) acc[j] = make_float2(0.f, 0.f);
    #pragma unroll 8
    for (int n2 = 0; n2 < 32; n2++) {
        float2 a = sA[r * 32 + n2];
        for (int j = 0; j < 4; j++) {
            float2 f = tabs[n2 * 32 + c0 + j];
            acc[j].x += a.x * f.x - a.y * f.y;
            acc[j].y += a.x * f.y + a.y * f.x;
        }
    }
    for (int j = 0; j < 4; j++) {
        int k2 = c0 + j;
        int m = (k2 & 3) | ((k2 >> 3) << 2);
        int hl = (k2 >> 2) & 1;
        kf_cd[h * 1024 + m * 64 + hl * 32 + r] = acc[j];
    }
}

// C/D accumulator (col=lane&31, row=(m&3)+8*(m>>2)+4*(lane>>5)) -> bf16 A/B
// fragment (k = 16t+8*(lane>>5)+e). Pack to bf16 pairs FIRST, then one packed
// shfl per cross-half word.
static __device__ __forceinline__ void convertH(const f32x16& acc, bool hihalf, FragH& out) {
    unsigned P[8];
    #pragma unroll
    for (int j = 0; j < 8; j++) P[j] = packbf(acc[2 * j], acc[2 * j + 1]);
    #pragma unroll
    for (int t = 0; t < 2; t++) {
        unsigned a0 = P[4 * t + 0], a1 = P[4 * t + 1];
        unsigned b0 = P[4 * t + 2], b1 = P[4 * t + 3];
        unsigned a0x = __shfl_xor(a0, 32), a1x = __shfl_xor(a1, 32);
        unsigned b0x = __shfl_xor(b0, 32), b1x = __shfl_xor(b1, 32);
        out.f[t].u[0] = hihalf ? b0x : a0;
        out.f[t].u[1] = hihalf ? b1x : a1;
        out.f[t].u[2] = hihalf ? b0  : a0x;
        out.f[t].u[3] = hihalf ? b1  : a1x;
    }
}

__global__ __launch_bounds__(256, 4) void conv_mfma(const float* __restrict__ u,
                                                    const float2* __restrict__ T1,
                                                    const uint4* __restrict__ Ftab,
                                                    const float2* __restrict__ KF,
                                                    float* __restrict__ out) {
    const int lane = threadIdx.x & 63;
    const int wave = threadIdx.x >> 6;
    const int w = blockIdx.x * 4 + wave;     // 0..8191, 2 tiles each
    const int h = w >> 6;                    // both tiles share h
    const int col = lane & 31;
    const int hl = lane >> 5;
    const bool hihalf = (hl != 0);

    // Fixed F fragment tables (bf16, hi only), register-resident.
    // F[0]=re=cos, F[1]=im=-sin, F[2]=+sin
    U F[3][2];
    #pragma unroll
    for (int c = 0; c < 3; c++)
        #pragma unroll
        for (int t = 0; t < 2; t++) {
            uint4 raw = Ftab[(c * 2 + t) * 64 + lane];
            F[c][t].u[0] = raw.x; F[c][t].u[1] = raw.y;
            F[c][t].u[2] = raw.z; F[c][t].u[3] = raw.w;
        }
    float2 t1[16], kf[16];
    #pragma unroll
    for (int m = 0; m < 16; m++) {
        t1[m] = T1[m * 64 + lane];
        kf[m] = KF[h * 1024 + m * 64 + lane];
    }

    const f32x16 Z16 = {0,0,0,0,0,0,0,0,0,0,0,0,0,0,0,0};

    for (int i = 0; i < 2; i++) {
        const int tile = w * 2 + i;
        const int b = tile & 127;
        const float* up = u + ((size_t)(b * 128 + h) << 10);

        // ---- Input: A = X^T direct from global, single bf16.
        U A[2];
        #pragma unroll
        for (int t = 0; t < 2; t++) {
            float xv[8];
            #pragma unroll
            for (int e = 0; e < 8; e++)
                xv[e] = up[(16 * t + 8 * hl + e) * 32 + col];
            #pragma unroll
            for (int v = 0; v < 4; v++)
                A[t].u[v] = packbf(xv[2 * v], xv[2 * v + 1]);
        }

        // ---- Stage 1: Y^T = X^T @ F
        f32x16 aR = Z16, aI = Z16;
        #pragma unroll
        for (int t = 0; t < 2; t++) {
            aR = MFMA(A[t], F[0][t], aR);
            aI = MFMA(A[t], F[1][t], aI);
        }
        #pragma unroll
        for (int m = 0; m < 16; m++) {                 // twiddle tw (has 1/N)
            float rr = aR[m] * t1[m].x - aI[m] * t1[m].y;
            float ii = aR[m] * t1[m].y + aI[m] * t1[m].x;
            aR[m] = rr; aI[m] = ii;
        }
        FragH Yr, Yi;
        convertH(aR, hihalf, Yr);
        convertH(aI, hihalf, Yi);

        // ---- Stage 3: Z^T = F @ Y^T  (Zr = re@Yr + sin@Yi ; Zi = re@Yi + im@Yr)
        f32x16 bR = Z16, bI = Z16;
        #pragma unroll
        for (int t = 0; t < 2; t++) {
            bR = MFMA(F[0][t], Yr.f[t], bR); bR = MFMA(F[2][t], Yi.f[t], bR);
            bI = MFMA(F[0][t], Yi.f[t], bI); bI = MFMA(F[1][t], Yr.f[t], bI);
        }
        #pragma unroll
        for (int m = 0; m < 16; m++) {                 // filter spectrum
            float rr = bR[m] * kf[m].x - bI[m] * kf[m].y;
            float ii = bR[m] * kf[m].y + bI[m] * kf[m].x;
            bR[m] = rr; bI[m] = ii;
        }
        FragH Zr, Zi;
        convertH(bR, hihalf, Zr);
        convertH(bI, hihalf, Zi);

        // ---- Stage 5: W = Z @ Finv  (Wr = Zr@re + Zi@im ; Wi = Zr@sin + Zi@re)
        aR = Z16; aI = Z16;
        #pragma unroll
        for (int t = 0; t < 2; t++) {
            aR = MFMA(Zr.f[t], F[0][t], aR); aR = MFMA(Zi.f[t], F[1][t], aR);
            aI = MFMA(Zr.f[t], F[2][t], aI); aI = MFMA(Zi.f[t], F[0][t], aI);
        }
        #pragma unroll
        for (int m = 0; m < 16; m++) {                 // twinv = 1024*conj(tw)
            float rr = 1024.0f * (aR[m] * t1[m].x + aI[m] * t1[m].y);
            float ii = 1024.0f * (aI[m] * t1[m].x - aR[m] * t1[m].y);
            aR[m] = rr; aI[m] = ii;
        }
        FragH Wr, Wi;
        convertH(aR, hihalf, Wr);
        convertH(aI, hihalf, Wi);

        // ---- Stage 7: y = Re(Finv @ W) = re@Wr + im@Wi
        f32x16 yR = Z16;
        #pragma unroll
        for (int t = 0; t < 2; t++) {
            yR = MFMA(F[0][t], Wr.f[t], yR);
            yR = MFMA(F[1][t], Wi.f[t], yR);
        }
        float* op = out + ((size_t)(b * 128 + h) << 10);
        #pragma unroll
        for (int m = 0; m < 16; m++)
            op[((m & 3) + 8 * (m >> 2) + 4 * hl) * 32 + col] = yR[m];
    }
}

extern "C" void kernel_launch(void* const* d_in, const int* in_sizes, int n_in,
                              void* d_out, int out_size, void* d_ws, size_t ws_size,
                              hipStream_t stream) {
    const float* u = (const float*)d_in[0];   // (B=128, H=128, N=1024)
    const float* k = (const float*)d_in[1];   // (H=128, N=1024)
    float* out = (float*)d_out;               // (B, H, N) float32

    float2* tabs  = (float2*)d_ws;
    float2* T1    = (float2*)((char*)d_ws + 32768);
    uint4*  Ftab  = (uint4*)((char*)d_ws + 49152);
    float2* kf_cd = (float2*)((char*)d_ws + 65536);

    fft_tables<<<16, 256, 0, stream>>>(tabs, T1, Ftab);
    kf_kernel<<<128, 256, 0, stream>>>(k, tabs, kf_cd);
    conv_mfma<<<2048, 256, 0, stream>>>(u, T1, Ftab, kf_cd, out);
}

// Round 5
// 50.625 us; speedup vs baseline: 1.4610x; 1.4610x over previous
//
#include <hip/hip_runtime.h>
#include <hip/hip_bf16.h>
#include <math.h>

typedef __attribute__((ext_vector_type(8))) short short8;
typedef __attribute__((ext_vector_type(16))) float f32x16;

union U {
    unsigned u[4];
    short8 s;
};

struct FragH {         // one component (re or im) bf16 operand, 2 k-tiles
    U f[2];
};

static __device__ __forceinline__ unsigned short f2bf(float x) {
    __bf16 b = (__bf16)x;                       // RNE, native v_cvt on gfx950
    return __builtin_bit_cast(unsigned short, b);
}
static __device__ __forceinline__ float bf2f(unsigned short h) {
    return __builtin_bit_cast(float, (unsigned)h << 16);
}
static __device__ __forceinline__ unsigned packbf(float a, float b) {
    return (unsigned)f2bf(a) | ((unsigned)f2bf(b) << 16);
}

#define MFMA(A, B, C) __builtin_amdgcn_mfma_f32_32x32x16_bf16((A).s, (B).s, (C), 0, 0, 0)

// ---------------------------------------------------------------------------
// Workspace layout (bytes):
//   0      : tabs  float2[4096]  (F, Finv, tw, twinv -- legacy layout for kf_kernel)
//   32768  : T1    float2[1024]  (tw permuted to C/D fragment order)
//   49152  : Ftab  uint4 [384]   (bf16 fragment tables: re, im, +sin)
//   65536  : kf_cd float2[128*1024] (filter spectrum, permuted to C/D order)
// ---------------------------------------------------------------------------

__global__ __launch_bounds__(256) void fft_tables(float2* tabs, float2* T1, uint4* Ftab) {
    int gid = blockIdx.x * 256 + threadIdx.x;       // grid 16*256 = 4096
    if (gid < 1024) {
        int i = gid;
        int r = i >> 5, c = i & 31;
        float s32, c32;
        sincospif((float)((r * c) & 31) / 16.0f, &s32, &c32);
        s32 = -s32;                                  // exp(-2pi i rc/32)
        tabs[i]        = make_float2(c32,  s32);     // F
        tabs[1024 + i] = make_float2(c32, -s32);     // Finv
        float sN, cN;
        sincospif((float)(r * c) / 512.0f, &sN, &cN);
        sN = -sN;                                    // exp(-2pi i rc/1024)
        tabs[2048 + i] = make_float2(cN / 1024.0f, sN / 1024.0f);  // tw
        tabs[3072 + i] = make_float2(cN, -sN);                     // twinv
        // T1[m][l] = tw[l&31][row(m,l)] (tw symmetric)
        int m = i >> 6, l = i & 63;
        int row = (m & 3) + 8 * (m >> 2) + 4 * (l >> 5);
        int prod = (l & 31) * row;
        float st, ct;
        sincospif((float)prod / 512.0f, &st, &ct);
        T1[i] = make_float2(ct / 1024.0f, -st / 1024.0f);
    }
    if (gid < 1536) {
        // Ftab: 3 comps x 2 ktiles x 64 lanes x 4 vgprs, packed bf16 pairs.
        // comp 0: re(F)=cos ; 1: im(F)=-sin ; 2: +sin
        int c = gid >> 9;
        int rem = gid & 511;
        int t = rem >> 8;
        int sub = rem & 255;
        int l = sub >> 2;
        int v = sub & 3;
        int k0 = 16 * t + 8 * (l >> 5) + 2 * v;
        int j = l & 31;
        unsigned short sh[2];
        for (int q = 0; q < 2; q++) {
            int k = k0 + q;
            float sa, ca;
            sincospif((float)((k * j) & 31) / 16.0f, &sa, &ca);
            float base = (c == 0) ? ca : ((c == 1) ? -sa : sa);
            sh[q] = f2bf(base);
        }
        ((unsigned*)Ftab)[((c * 2 + t) * 64 + l) * 4 + v] =
            (unsigned)sh[0] | ((unsigned)sh[1] << 16);
    }
}

// Filter spectrum kfT[h][k1][k2] = FFT_1024(k[h])[32*k2+k1], written permuted:
// kf_cd[h][m][l] = kfT[h][l&31][row(m,l)]
__global__ __launch_bounds__(256) void kf_kernel(const float* __restrict__ kin,
                                                 const float2* __restrict__ tabs,
                                                 float2* __restrict__ kf_cd) {
    __shared__ float  sx[1024];
    __shared__ float2 sA[1024];
    const int h = blockIdx.x, t = threadIdx.x;
    for (int i = t; i < 1024; i += 256) sx[i] = kin[h * 1024 + i];
    __syncthreads();
    const int r = t >> 3, c0 = (t & 7) << 2;

    float2 acc[4];
    for (int j = 0; j < 4; j++) acc[j] = make_float2(0.f, 0.f);
    #pragma unroll 8
    for (int n1 = 0; n1 < 32; n1++) {
        float2 f = tabs[r * 32 + n1];
        for (int j = 0; j < 4; j++) {
            float xv = sx[n1 * 32 + c0 + j];
            acc[j].x += f.x * xv;
            acc[j].y += f.y * xv;
        }
    }
    for (int j = 0; j < 4; j++) {
        float2 w = tabs[3072 + r * 32 + c0 + j];   // conj -> exp(-2pi i rc/N)
        sA[r * 32 + c0 + j] = make_float2(acc[j].x * w.x + acc[j].y * w.y,
                                          acc[j].y * w.x - acc[j].x * w.y);
    }
    __syncthreads();
    for (int j = 0; j < 4; j++) acc[j] = make_float2(0.f, 0.f);
    #pragma unroll 8
    for (int n2 = 0; n2 < 32; n2++) {
        float2 a = sA[r * 32 + n2];
        for (int j = 0; j < 4; j++) {
            float2 f = tabs[n2 * 32 + c0 + j];
            acc[j].x += a.x * f.x - a.y * f.y;
            acc[j].y += a.x * f.y + a.y * f.x;
        }
    }
    for (int j = 0; j < 4; j++) {
        int k2 = c0 + j;
        int m = (k2 & 3) | ((k2 >> 3) << 2);
        int hl = (k2 >> 2) & 1;
        kf_cd[h * 1024 + m * 64 + hl * 32 + r] = acc[j];
    }
}

// C/D accumulator (col=lane&31, row=(m&3)+8*(m>>2)+4*(lane>>5)) -> bf16 A/B
// fragment (k = 16t+8*(lane>>5)+e). Pack to bf16 pairs FIRST, then one packed
// shfl per cross-half word.
static __device__ __forceinline__ void convertH(const f32x16& acc, bool hihalf, FragH& out) {
    unsigned P[8];
    #pragma unroll
    for (int j = 0; j < 8; j++) P[j] = packbf(acc[2 * j], acc[2 * j + 1]);
    #pragma unroll
    for (int t = 0; t < 2; t++) {
        unsigned a0 = P[4 * t + 0], a1 = P[4 * t + 1];
        unsigned b0 = P[4 * t + 2], b1 = P[4 * t + 3];
        unsigned a0x = __shfl_xor(a0, 32), a1x = __shfl_xor(a1, 32);
        unsigned b0x = __shfl_xor(b0, 32), b1x = __shfl_xor(b1, 32);
        out.f[t].u[0] = hihalf ? b0x : a0;
        out.f[t].u[1] = hihalf ? b1x : a1;
        out.f[t].u[2] = hihalf ? b0  : a0x;
        out.f[t].u[3] = hihalf ? b1  : a1x;
    }
}

// launch_bounds (256,2): R4's (256,4) forced VGPR 120->64 and spilled
// (~200 MB of scratch HBM traffic, dur 54->74us). Keep the allocator free.
__global__ __launch_bounds__(256, 2) void conv_mfma(const float* __restrict__ u,
                                                    const float2* __restrict__ T1,
                                                    const uint4* __restrict__ Ftab,
                                                    const float2* __restrict__ KF,
                                                    float* __restrict__ out) {
    const int lane = threadIdx.x & 63;
    const int wave = threadIdx.x >> 6;
    const int w = blockIdx.x * 4 + wave;     // 0..8191, 2 tiles each
    const int h = w >> 6;                    // both tiles share h
    const int col = lane & 31;
    const int hl = lane >> 5;
    const bool hihalf = (hl != 0);

    // Fixed F fragment tables (bf16), register-resident.
    // F[0]=re=cos, F[1]=im=-sin, F[2]=+sin
    U F[3][2];
    #pragma unroll
    for (int c = 0; c < 3; c++)
        #pragma unroll
        for (int t = 0; t < 2; t++) {
            uint4 raw = Ftab[(c * 2 + t) * 64 + lane];
            F[c][t].u[0] = raw.x; F[c][t].u[1] = raw.y;
            F[c][t].u[2] = raw.z; F[c][t].u[3] = raw.w;
        }
    float2 t1[16], kf[16];
    #pragma unroll
    for (int m = 0; m < 16; m++) {
        t1[m] = T1[m * 64 + lane];
        kf[m] = KF[h * 1024 + m * 64 + lane];
    }

    const f32x16 Z16 = {0,0,0,0,0,0,0,0,0,0,0,0,0,0,0,0};

    // ---- Prefetch BOTH tiles' inputs up front (independent loads; tile 1's
    // ~900-cycle HBM latency hides under tile 0's compute chain).
    U A[2][2];
    #pragma unroll
    for (int i = 0; i < 2; i++) {
        const int b = (w * 2 + i) & 127;
        const float* up = u + ((size_t)(b * 128 + h) << 10);
        #pragma unroll
        for (int t = 0; t < 2; t++) {
            float xv[8];
            #pragma unroll
            for (int e = 0; e < 8; e++)
                xv[e] = up[(16 * t + 8 * hl + e) * 32 + col];
            #pragma unroll
            for (int v = 0; v < 4; v++)
                A[i][t].u[v] = packbf(xv[2 * v], xv[2 * v + 1]);
        }
    }

    #pragma unroll
    for (int i = 0; i < 2; i++) {
        const int b = (w * 2 + i) & 127;

        // ---- Stage 1: Y^T = X^T @ F
        f32x16 aR = Z16, aI = Z16;
        #pragma unroll
        for (int t = 0; t < 2; t++) {
            aR = MFMA(A[i][t], F[0][t], aR);
            aI = MFMA(A[i][t], F[1][t], aI);
        }
        #pragma unroll
        for (int m = 0; m < 16; m++) {                 // twiddle tw (has 1/N)
            float rr = aR[m] * t1[m].x - aI[m] * t1[m].y;
            float ii = aR[m] * t1[m].y + aI[m] * t1[m].x;
            aR[m] = rr; aI[m] = ii;
        }
        FragH Yr, Yi;
        convertH(aR, hihalf, Yr);
        convertH(aI, hihalf, Yi);

        // ---- Stage 3: Z^T = F @ Y^T  (Zr = re@Yr + sin@Yi ; Zi = re@Yi + im@Yr)
        f32x16 bR = Z16, bI = Z16;
        #pragma unroll
        for (int t = 0; t < 2; t++) {
            bR = MFMA(F[0][t], Yr.f[t], bR); bR = MFMA(F[2][t], Yi.f[t], bR);
            bI = MFMA(F[0][t], Yi.f[t], bI); bI = MFMA(F[1][t], Yr.f[t], bI);
        }
        #pragma unroll
        for (int m = 0; m < 16; m++) {                 // filter spectrum
            float rr = bR[m] * kf[m].x - bI[m] * kf[m].y;
            float ii = bR[m] * kf[m].y + bI[m] * kf[m].x;
            bR[m] = rr; bI[m] = ii;
        }
        FragH Zr, Zi;
        convertH(bR, hihalf, Zr);
        convertH(bI, hihalf, Zi);

        // ---- Stage 5: W = Z @ Finv  (Wr = Zr@re + Zi@im ; Wi = Zr@sin + Zi@re)
        aR = Z16; aI = Z16;
        #pragma unroll
        for (int t = 0; t < 2; t++) {
            aR = MFMA(Zr.f[t], F[0][t], aR); aR = MFMA(Zi.f[t], F[1][t], aR);
            aI = MFMA(Zr.f[t], F[2][t], aI); aI = MFMA(Zi.f[t], F[0][t], aI);
        }
        #pragma unroll
        for (int m = 0; m < 16; m++) {                 // twinv = 1024*conj(tw)
            float rr = 1024.0f * (aR[m] * t1[m].x + aI[m] * t1[m].y);
            float ii = 1024.0f * (aI[m] * t1[m].x - aR[m] * t1[m].y);
            aR[m] = rr; aI[m] = ii;
        }
        FragH Wr, Wi;
        convertH(aR, hihalf, Wr);
        convertH(aI, hihalf, Wi);

        // ---- Stage 7: y = Re(Finv @ W) = re@Wr + im@Wi
        f32x16 yR = Z16;
        #pragma unroll
        for (int t = 0; t < 2; t++) {
            yR = MFMA(F[0][t], Wr.f[t], yR);
            yR = MFMA(F[1][t], Wi.f[t], yR);
        }
        float* op = out + ((size_t)(b * 128 + h) << 10);
        #pragma unroll
        for (int m = 0; m < 16; m++)
            op[((m & 3) + 8 * (m >> 2) + 4 * hl) * 32 + col] = yR[m];
    }
}

extern "C" void kernel_launch(void* const* d_in, const int* in_sizes, int n_in,
                              void* d_out, int out_size, void* d_ws, size_t ws_size,
                              hipStream_t stream) {
    const float* u = (const float*)d_in[0];   // (B=128, H=128, N=1024)
    const float* k = (const float*)d_in[1];   // (H=128, N=1024)
    float* out = (float*)d_out;               // (B, H, N) float32

    float2* tabs  = (float2*)d_ws;
    float2* T1    = (float2*)((char*)d_ws + 32768);
    uint4*  Ftab  = (uint4*)((char*)d_ws + 49152);
    float2* kf_cd = (float2*)((char*)d_ws + 65536);

    fft_tables<<<16, 256, 0, stream>>>(tabs, T1, Ftab);
    kf_kernel<<<128, 256, 0, stream>>>(k, tabs, kf_cd);
    conv_mfma<<<2048, 256, 0, stream>>>(u, T1, Ftab, kf_cd, out);
}